// Round 19
// baseline (117.617 us; speedup 1.0000x reference)
//
#include <hip/hip_runtime.h>
#include <hip/hip_bf16.h>
#include <stdint.h>

// ============================================================================
// Fused causal self-attention block: QKV projection + flash attention.
// bf16 MFMA. No-max softmax (scores bounded; log2e folded into Q scale).
// R19 k_attn: 32-row kv tiles -> LDS 32KB (dbuf K+V) -> 4 blocks/CU, all 576
// blocks co-resident. 32x32 MFMA, in-register P (lane^32 bpermute exchange),
// counted vmcnt(4). Same decode/partials/k_comb as R18.
// k_qkv: triple-buffered, one barrier/iter, counted vmcnt(4) (R18).
// ============================================================================

typedef __bf16 bf16x8 __attribute__((ext_vector_type(8)));
typedef float  f32x4  __attribute__((ext_vector_type(4)));
typedef float  f32x16 __attribute__((ext_vector_type(16)));
typedef unsigned int u32x4 __attribute__((ext_vector_type(4)));
typedef unsigned int u32x2 __attribute__((ext_vector_type(2)));

using bf16 = __hip_bfloat16;

#define AS1 __attribute__((address_space(1)))
#define AS3 __attribute__((address_space(3)))

__device__ __forceinline__ void gl_lds16(const void* g, void* l) {
  __builtin_amdgcn_global_load_lds((AS1 uint32_t*)g, (AS3 uint32_t*)l, 16, 0, 0);
}

__device__ __forceinline__ void wait_vm4() {
  asm volatile("s_waitcnt vmcnt(4)" ::: "memory");
  __builtin_amdgcn_sched_barrier(0);
}
__device__ __forceinline__ void wait_vm0() {
  asm volatile("s_waitcnt vmcnt(0)" ::: "memory");
  __builtin_amdgcn_sched_barrier(0);
}

// ---------------------------------------------------------------------------
// 1) W [1024][128] fp32 -> Wt[z][128][1024] bf16 (transpose via LDS tile)
// ---------------------------------------------------------------------------
__global__ __launch_bounds__(256) void k_wt(const float* __restrict__ Wq,
                                            const float* __restrict__ Wk,
                                            const float* __restrict__ Wv,
                                            bf16* __restrict__ Wt) {
  __shared__ bf16 t[64][72];
  const float* W = blockIdx.z == 0 ? Wq : (blockIdx.z == 1 ? Wk : Wv);
  int k0 = blockIdx.x * 64, n0 = blockIdx.y * 64;
  int tid = threadIdx.x;
  int r = tid >> 4, c4 = (tid & 15) * 4;
#pragma unroll
  for (int s = 0; s < 4; ++s) {
    int rr = r + s * 16;
    float4 v = *(const float4*)(W + (size_t)(k0 + rr) * 128 + n0 + c4);
    t[rr][c4 + 0] = __float2bfloat16(v.x);
    t[rr][c4 + 1] = __float2bfloat16(v.y);
    t[rr][c4 + 2] = __float2bfloat16(v.z);
    t[rr][c4 + 3] = __float2bfloat16(v.w);
  }
  __syncthreads();
  bf16* out = Wt + (size_t)blockIdx.z * 128 * 1024;
#pragma unroll
  for (int s = 0; s < 4; ++s) {
    int rn = r + s * 16;
    union { bf16 h[4]; u32x2 v; } u;
    u.h[0] = t[c4 + 0][rn]; u.h[1] = t[c4 + 1][rn];
    u.h[2] = t[c4 + 2][rn]; u.h[3] = t[c4 + 3][rn];
    *(u32x2*)(out + (size_t)(n0 + rn) * 1024 + k0 + c4) = u.v;
  }
}

// ---------------------------------------------------------------------------
// 2) fused QKV projection + in-kernel V transpose (R18: triple-buffered,
//    one barrier/iter, counted vmcnt(4)). BM=64, grid 256, 512 thr.
// ---------------------------------------------------------------------------
__global__ __launch_bounds__(512) void k_qkv(const float* __restrict__ X,
                                             const bf16* __restrict__ Wt,
                                             const float* __restrict__ bq,
                                             const float* __restrict__ bk,
                                             const float* __restrict__ bv,
                                             bf16* __restrict__ Qo,
                                             bf16* __restrict__ Ko,
                                             bf16* __restrict__ Vt) {
  __shared__ __align__(16) char smem[98304];
  float* Xs = (float*)smem;                  // [3][64*32] f32, 24 KB
  bf16* Ws = (bf16*)(smem + 24576);          // [3][3*128*32] bf16, 72 KB
  bf16* Vs = (bf16*)smem;                    // epilogue: [64][136], 17.4 KB

  const int m0 = blockIdx.x * 64;
  const int tid = threadIdx.x;
  const int lane = tid & 63;
  const int li = lane & 15, g = lane >> 4;
  const int wid = tid >> 6;
  const int wm = wid >> 2, wn = wid & 3;

  const int xr = tid >> 3;
  const int xc32 = (tid & 7) >> 1;
  const int xhf = tid & 1;
  const int wr = tid >> 2;
  const int wc = tid & 3;

  f32x4 acc[3][2][2] = {};

  {
    gl_lds16(X + (size_t)(m0 + xr) * 1024 + (xc32 ^ (xr & 3)) * 8 + xhf * 4,
             Xs + tid * 4);
#pragma unroll
    for (int z = 0; z < 3; ++z)
      gl_lds16(Wt + (size_t)z * 131072 + (size_t)wr * 1024 + (wc ^ (wr & 3)) * 8,
               Ws + z * 4096 + tid * 8);
  }
  int cur = 0, nxt = 1;
  for (int kt = 0; kt < 32; ++kt) {
    if (kt < 31) {
      const int k0 = (kt + 1) * 32;
      gl_lds16(X + (size_t)(m0 + xr) * 1024 + k0 + (xc32 ^ (xr & 3)) * 8 + xhf * 4,
               Xs + nxt * 2048 + tid * 4);
#pragma unroll
      for (int z = 0; z < 3; ++z)
        gl_lds16(Wt + (size_t)z * 131072 + (size_t)wr * 1024 + k0 + (wc ^ (wr & 3)) * 8,
                 Ws + nxt * 12288 + z * 4096 + tid * 8);
      wait_vm4();
    } else {
      wait_vm0();
    }
    __builtin_amdgcn_s_barrier();

    bf16x8 af[2];
#pragma unroll
    for (int mf = 0; mf < 2; ++mf) {
      int r = wm * 32 + mf * 16 + li;
      const float* xp = Xs + cur * 2048 + r * 32 + ((g ^ (r & 3)) * 8);
      f32x4 x0 = *(const f32x4*)xp;
      f32x4 x1 = *(const f32x4*)(xp + 4);
      union { bf16 h[8]; bf16x8 v; } u;
      u.h[0] = __float2bfloat16(x0[0]); u.h[1] = __float2bfloat16(x0[1]);
      u.h[2] = __float2bfloat16(x0[2]); u.h[3] = __float2bfloat16(x0[3]);
      u.h[4] = __float2bfloat16(x1[0]); u.h[5] = __float2bfloat16(x1[1]);
      u.h[6] = __float2bfloat16(x1[2]); u.h[7] = __float2bfloat16(x1[3]);
      af[mf] = u.v;
    }
#pragma unroll
    for (int z = 0; z < 3; ++z) {
#pragma unroll
      for (int nf = 0; nf < 2; ++nf) {
        int r = wn * 32 + nf * 16 + li;
        bf16x8 bfrag =
            *(const bf16x8*)(Ws + cur * 12288 + z * 4096 + r * 32 + ((g ^ (r & 3)) * 8));
#pragma unroll
        for (int mf = 0; mf < 2; ++mf)
          acc[z][mf][nf] = __builtin_amdgcn_mfma_f32_16x16x32_bf16(
              af[mf], bfrag, acc[z][mf][nf], 0, 0, 0);
      }
    }
    cur = nxt;
    nxt = nxt == 2 ? 0 : nxt + 1;
  }

#pragma unroll
  for (int z = 0; z < 2; ++z) {
    const float* bias = z == 0 ? bq : bk;
    bf16* Out = z == 0 ? Qo : Ko;
    const float scale = z == 0 ? 0.12752404368678202f : 1.0f;
#pragma unroll
    for (int nf = 0; nf < 2; ++nf) {
      int col = wn * 32 + nf * 16 + li;
      float bb = bias[col];
#pragma unroll
      for (int mf = 0; mf < 2; ++mf)
#pragma unroll
        for (int j = 0; j < 4; ++j) {
          int row = m0 + wm * 32 + mf * 16 + g * 4 + j;
          Out[(size_t)row * 128 + col] =
              __float2bfloat16((acc[z][mf][nf][j] + bb) * scale);
        }
    }
  }

  __syncthreads();
#pragma unroll
  for (int nf = 0; nf < 2; ++nf) {
    int col = wn * 32 + nf * 16 + li;
    float bb = bv[col];
#pragma unroll
    for (int mf = 0; mf < 2; ++mf)
#pragma unroll
      for (int j = 0; j < 4; ++j) {
        int row = wm * 32 + mf * 16 + g * 4 + j;
        Vs[row * 136 + col] = __float2bfloat16(acc[2][mf][nf][j] + bb);
      }
  }
  __syncthreads();
  const int b = m0 >> 12;
  const int s_off = m0 & 4095;
#pragma unroll
  for (int t2 = 0; t2 < 2; ++t2) {
    int idx = tid + 512 * t2;
    int dv = idx & 127;
    int sg = idx >> 7;
    union { bf16 h[8]; u32x4 v; } u;
#pragma unroll
    for (int si = 0; si < 8; ++si) u.h[si] = Vs[(sg * 8 + si) * 136 + dv];
    *(u32x4*)(Vt + (size_t)(b * 128 + dv) * 4096 + s_off + sg * 8) = u.v;
  }
}

// ---------------------------------------------------------------------------
// 3) causal flash attention v14: 32-row kv tiles, 32x32 MFMA, in-register P.
//    256 thr = 4 waves x 32 q-rows (q-tile 128). LDS 32KB (dbuf K+V) ->
//    4 blocks/CU; all 576 blocks co-resident. ntiles = 4qt+4 (32-kv units),
//    nch = (qt+4)>>2 — same chunk boundaries/work per block as R18.
// ---------------------------------------------------------------------------
__global__ __launch_bounds__(256, 4) void k_attn(const bf16* __restrict__ Qb,
                                                 const bf16* __restrict__ Kb,
                                                 const bf16* __restrict__ Vt,
                                                 bf16* __restrict__ o_part,
                                                 float* __restrict__ l_part) {
  __shared__ __align__(16) bf16 Kls[2][32 * 128];  // 16 KB [kv][d] swizzled
  __shared__ __align__(16) bf16 Vls[2][128 * 32];  // 16 KB [dv][kv] swizzled

  const int bid = blockIdx.x;
  const int xcd = bid & 7;
  const int slot = xcd * 72 + (bid >> 3);     // bijective (576 = 8*72)
  const int b = slot / 144;
  const int s = 143 - (slot - b * 144);       // heavy-first work index
  const int widx = b * 144 + s;               // partial index (k_comb's)
  int qt = 0;
#pragma unroll
  for (int q2 = 1; q2 < 32; ++q2) {
    int M = q2 >> 2;
    if ((M + 1) * (2 * M + (q2 & 3)) <= s) qt = q2;
  }
  const int Mq = qt >> 2;
  const int chunk = s - (Mq + 1) * (2 * Mq + (qt & 3));
  const int ntiles = 4 * qt + 4;              // 32-kv tiles
  const int nch = (qt + 4) >> 2;
  const int clen = ntiles / nch;
  const int crem = ntiles - clen * nch;
  const int kt0 = chunk * clen + min(chunk, crem);
  const int kt1 = kt0 + clen + (chunk < crem ? 1 : 0) - 1;

  const int tid = threadIdx.x;
  const int lane = tid & 63;
  const int l31 = lane & 31;                  // q (and kv/dv row) index
  const int hl = lane >> 5;                   // lane half (k-dim half)
  const int w = tid >> 6;                     // wave 0..3, owns 32 q-rows

  const int qrow = b * 4096 + qt * 128 + w * 32 + l31;
  bf16x8 qf[8];
#pragma unroll
  for (int ks = 0; ks < 8; ++ks)
    qf[ks] = *(const bf16x8*)(Qb + (size_t)qrow * 128 + ks * 16 + hl * 8);

  f32x16 o[4] = {};
  f32x16 lacc = {};
  bf16x8 ones;
#pragma unroll
  for (int e = 0; e < 8; ++e) ones[e] = (__bf16)1.0f;

  const bf16* Vtb = Vt + (size_t)b * 128 * 4096;
  const int xaddr = (lane ^ 32) << 2;         // ds_bpermute byte addr

  // prologue: stage K+V 32-kv tile kt0 -> buf 0 (4 loads/thread)
  {
    const int kv0 = kt0 * 32;
#pragma unroll
    for (int ii = 0; ii < 2; ++ii) {
      int c = tid + 256 * ii;                 // 0..511
      int r = c >> 4, cc = c & 15;            // K: 32 rows x 16 chunks
      gl_lds16(Kb + (size_t)(b * 4096 + kv0 + r) * 128 + (cc ^ (r & 7)) * 8,
               &Kls[0][c * 8]);
      int r2 = c >> 2, cc2 = c & 3;           // V: 128 rows x 4 chunks
      gl_lds16(Vtb + (size_t)r2 * 4096 + kv0 + ((cc2 ^ ((r2 >> 1) & 3)) * 8),
               &Vls[0][c * 8]);
    }
  }
  int cur = 0;
  for (int kt = kt0; kt <= kt1; ++kt) {
    if (kt < kt1) {
      const int kv0n = (kt + 1) * 32;
#pragma unroll
      for (int ii = 0; ii < 2; ++ii) {
        int c = tid + 256 * ii;
        int r = c >> 4, cc = c & 15;
        gl_lds16(Kb + (size_t)(b * 4096 + kv0n + r) * 128 + (cc ^ (r & 7)) * 8,
                 &Kls[cur ^ 1][c * 8]);
        int r2 = c >> 2, cc2 = c & 3;
        gl_lds16(Vtb + (size_t)r2 * 4096 + kv0n + ((cc2 ^ ((r2 >> 1) & 3)) * 8),
                 &Vls[cur ^ 1][c * 8]);
      }
      wait_vm4();
    } else {
      wait_vm0();
    }
    __builtin_amdgcn_s_barrier();  // tile kt ready in buf[cur]

    const bf16* Kl = &Kls[cur][0];
    const bf16* Vl = &Vls[cur][0];
    const int kv0 = kt * 32;

    // S^T = K Q^T : st = C[kv (32 rows)][q], A=K rows, B=Q^T
    f32x16 st = {};
#pragma unroll
    for (int ks = 0; ks < 8; ++ks) {
      int r = l31;
      int ch = (2 * ks + hl) ^ (r & 7);
      bf16x8 kf = *(const bf16x8*)(Kl + r * 128 + ch * 8);
      st = __builtin_amdgcn_mfma_f32_32x32x16_bf16(kf, qf[ks], st, 0, 0, 0);
    }

    if (kt >= 4 * qt) {  // diagonal tiles: causal mask (kv > q)
      const int dk = kv0 - qt * 128;
      const int qloc = w * 32 + l31;
#pragma unroll
      for (int reg = 0; reg < 16; ++reg) {
        int kvl = dk + (reg & 3) + 8 * (reg >> 2) + 4 * hl;
        if (kvl > qloc) st[reg] = -1e30f;
      }
    }

    // P = exp2(S) in-register; pack to bf16 dwords
    uint32_t D[8];
#pragma unroll
    for (int i = 0; i < 8; ++i) {
      union { bf16 h2[2]; uint32_t u; } pu;
      pu.h2[0] = __float2bfloat16(exp2f(st[2 * i]));
      pu.h2[1] = __float2bfloat16(exp2f(st[2 * i + 1]));
      D[i] = pu.u;
    }

    // lane^32 exchange
    uint32_t Z[2][2];
#pragma unroll
    for (int s2 = 0; s2 < 2; ++s2)
#pragma unroll
      for (int j = 0; j < 2; ++j) {
        uint32_t Y = hl ? D[4 * s2 + j] : D[4 * s2 + 2 + j];
        Z[s2][j] = (uint32_t)__builtin_amdgcn_ds_bpermute(xaddr, (int)Y);
      }

    // PV: O^T[dv][q] += V^T P^T per kv 16-slice; l via ones-MFMA
#pragma unroll
    for (int s2 = 0; s2 < 2; ++s2) {
      union { uint32_t u[4]; bf16x8 v; } pb;
      pb.u[0] = hl ? Z[s2][0] : D[4 * s2];
      pb.u[1] = hl ? Z[s2][1] : D[4 * s2 + 1];
      pb.u[2] = hl ? D[4 * s2 + 2] : Z[s2][0];
      pb.u[3] = hl ? D[4 * s2 + 3] : Z[s2][1];
#pragma unroll
      for (int ds = 0; ds < 4; ++ds) {
        int r = ds * 32 + l31;
        int ch = (2 * s2 + hl) ^ ((r >> 1) & 3);
        bf16x8 vf = *(const bf16x8*)(Vl + r * 32 + ch * 8);
        o[ds] = __builtin_amdgcn_mfma_f32_32x32x16_bf16(
            vf, pb.v, o[ds], 0, 0, 0);
      }
      lacc = __builtin_amdgcn_mfma_f32_32x32x16_bf16(
          ones, pb.v, lacc, 0, 0, 0);
    }
    __builtin_amdgcn_s_barrier();  // readers done before buf[cur] overwrite
    cur ^= 1;
  }

  // partials at WORK index widx
  bf16* op = o_part + (size_t)widx * (128 * 128);
  float* lp = l_part + widx * 128;
  const int qloc = w * 32 + l31;
  if (hl == 0) lp[qloc] = lacc[0];
#pragma unroll
  for (int ds = 0; ds < 4; ++ds)
#pragma unroll
    for (int a = 0; a < 4; ++a) {
      union { bf16 h4[4]; u32x2 v; } u;
#pragma unroll
      for (int j = 0; j < 4; ++j)
        u.h4[j] = __float2bfloat16(o[ds][4 * a + j]);
      *(u32x2*)(op + (size_t)qloc * 128 + ds * 32 + 8 * a + 4 * hl) = u.v;
    }
}

// ---------------------------------------------------------------------------
// 4) combine chunk partials: 8 cols/thread (u32x4 loads). (R16 verbatim)
// ---------------------------------------------------------------------------
__global__ __launch_bounds__(256) void k_comb(const bf16* __restrict__ op,
                                              const float* __restrict__ lp,
                                              float* __restrict__ out) {
  int i = blockIdx.x * 256 + threadIdx.x;  // 8-col group index, < 262144
  int row = i >> 4;
  int col8 = (i & 15) * 8;
  int b = row >> 12;
  int rb = row & 4095;
  int qt = rb >> 7;
  int lr = rb & 127;
  int M = qt >> 2;
  int base = b * 144 + (M + 1) * (2 * M + (qt & 3));
  int n = (qt + 4) >> 2;
  float l = 0.0f;
  float acc[8] = {};
  for (int c = 0; c < n; ++c) {
    l += lp[(base + c) * 128 + lr];
    union { bf16 h[8]; u32x4 v; } u;
    u.v = *(const u32x4*)(op + (size_t)(base + c) * 16384 + lr * 128 + col8);
#pragma unroll
    for (int j = 0; j < 8; ++j) acc[j] += __bfloat162float(u.h[j]);
  }
  float linv = 1.0f / l;
  float4 r0, r1;
  r0.x = acc[0] * linv; r0.y = acc[1] * linv;
  r0.z = acc[2] * linv; r0.w = acc[3] * linv;
  r1.x = acc[4] * linv; r1.y = acc[5] * linv;
  r1.z = acc[6] * linv; r1.w = acc[7] * linv;
  ((float4*)out)[i * 2] = r0;
  ((float4*)out)[i * 2 + 1] = r1;
}

// ---------------------------------------------------------------------------
extern "C" void kernel_launch(void* const* d_in, const int* in_sizes, int n_in,
                              void* d_out, int out_size, void* d_ws, size_t ws_size,
                              hipStream_t stream) {
  const float* X  = (const float*)d_in[0];
  const float* Wq = (const float*)d_in[1];
  const float* bq = (const float*)d_in[2];
  const float* Wk = (const float*)d_in[3];
  const float* bk = (const float*)d_in[4];
  const float* Wv = (const float*)d_in[5];
  const float* bv = (const float*)d_in[6];
  float* out = (float*)d_out;

  char* ws = (char*)d_ws;
  // layout (bytes) — fully disjoint, extent 32,538,624 (proven size)
  bf16* Wt  = (bf16*)(ws + 0);              //    786,432
  bf16* Qb  = (bf16*)(ws + 786432);         //  4,194,304
  bf16* Kb  = (bf16*)(ws + 4980736);        //  4,194,304
  bf16* Vt  = (bf16*)(ws + 9175040);        //  4,194,304
  bf16* o_part = (bf16*)(ws + 13369344);    // 18,874,368 (576*128*128*2)
  float* l_part = (float*)(ws + 32243712);  //    294,912

  k_wt<<<dim3(16, 2, 3), dim3(256), 0, stream>>>(Wq, Wk, Wv, Wt);
  k_qkv<<<dim3(256), dim3(512), 0, stream>>>(X, Wt, bq, bk, bv, Qb, Kb, Vt);
  k_attn<<<dim3(576), dim3(256), 0, stream>>>(Qb, Kb, Vt, o_part, l_part);
  k_comb<<<dim3(1024), dim3(256), 0, stream>>>(o_part, l_part, out);
}

// Round 20
// 81.052 us; speedup vs baseline: 1.4511x; 1.4511x over previous
//
#include <hip/hip_runtime.h>
#include <hip/hip_bf16.h>
#include <stdint.h>

// ============================================================================
// Fused causal self-attention block: QKV projection + flash attention.
// bf16 MFMA. No-max softmax (scores bounded; log2e folded into Q scale).
// R20 = R18 verbatim (session best, 81.1us):
//  - k_qkv: triple-buffered, ONE barrier/iter, counted vmcnt(4).
//  - k_attn: 64-kv tiles, dbuf K+V (2 blocks/CU), 32x32 MFMA, in-register P
//    (lane^32 ds_bpermute exchange), counted vmcnt(8).
//  - k_comb: 8 cols/thread.
// ============================================================================

typedef __bf16 bf16x8 __attribute__((ext_vector_type(8)));
typedef float  f32x4  __attribute__((ext_vector_type(4)));
typedef float  f32x16 __attribute__((ext_vector_type(16)));
typedef unsigned int u32x4 __attribute__((ext_vector_type(4)));
typedef unsigned int u32x2 __attribute__((ext_vector_type(2)));

using bf16 = __hip_bfloat16;

#define AS1 __attribute__((address_space(1)))
#define AS3 __attribute__((address_space(3)))

__device__ __forceinline__ void gl_lds16(const void* g, void* l) {
  __builtin_amdgcn_global_load_lds((AS1 uint32_t*)g, (AS3 uint32_t*)l, 16, 0, 0);
}

__device__ __forceinline__ void wait_vm4() {
  asm volatile("s_waitcnt vmcnt(4)" ::: "memory");
  __builtin_amdgcn_sched_barrier(0);
}
__device__ __forceinline__ void wait_vm8() {
  asm volatile("s_waitcnt vmcnt(8)" ::: "memory");
  __builtin_amdgcn_sched_barrier(0);
}
__device__ __forceinline__ void wait_vm0() {
  asm volatile("s_waitcnt vmcnt(0)" ::: "memory");
  __builtin_amdgcn_sched_barrier(0);
}

// ---------------------------------------------------------------------------
// 1) W [1024][128] fp32 -> Wt[z][128][1024] bf16 (transpose via LDS tile)
// ---------------------------------------------------------------------------
__global__ __launch_bounds__(256) void k_wt(const float* __restrict__ Wq,
                                            const float* __restrict__ Wk,
                                            const float* __restrict__ Wv,
                                            bf16* __restrict__ Wt) {
  __shared__ bf16 t[64][72];
  const float* W = blockIdx.z == 0 ? Wq : (blockIdx.z == 1 ? Wk : Wv);
  int k0 = blockIdx.x * 64, n0 = blockIdx.y * 64;
  int tid = threadIdx.x;
  int r = tid >> 4, c4 = (tid & 15) * 4;
#pragma unroll
  for (int s = 0; s < 4; ++s) {
    int rr = r + s * 16;
    float4 v = *(const float4*)(W + (size_t)(k0 + rr) * 128 + n0 + c4);
    t[rr][c4 + 0] = __float2bfloat16(v.x);
    t[rr][c4 + 1] = __float2bfloat16(v.y);
    t[rr][c4 + 2] = __float2bfloat16(v.z);
    t[rr][c4 + 3] = __float2bfloat16(v.w);
  }
  __syncthreads();
  bf16* out = Wt + (size_t)blockIdx.z * 128 * 1024;
#pragma unroll
  for (int s = 0; s < 4; ++s) {
    int rn = r + s * 16;
    union { bf16 h[4]; u32x2 v; } u;
    u.h[0] = t[c4 + 0][rn]; u.h[1] = t[c4 + 1][rn];
    u.h[2] = t[c4 + 2][rn]; u.h[3] = t[c4 + 3][rn];
    *(u32x2*)(out + (size_t)(n0 + rn) * 1024 + k0 + c4) = u.v;
  }
}

// ---------------------------------------------------------------------------
// 2) fused QKV projection + in-kernel V transpose. Triple-buffered,
//    ONE barrier per iter, counted vmcnt(4). BM=64, grid 256, 512 thr.
// ---------------------------------------------------------------------------
__global__ __launch_bounds__(512) void k_qkv(const float* __restrict__ X,
                                             const bf16* __restrict__ Wt,
                                             const float* __restrict__ bq,
                                             const float* __restrict__ bk,
                                             const float* __restrict__ bv,
                                             bf16* __restrict__ Qo,
                                             bf16* __restrict__ Ko,
                                             bf16* __restrict__ Vt) {
  __shared__ __align__(16) char smem[98304];
  float* Xs = (float*)smem;                  // [3][64*32] f32, 24 KB
  bf16* Ws = (bf16*)(smem + 24576);          // [3][3*128*32] bf16, 72 KB
  bf16* Vs = (bf16*)smem;                    // epilogue: [64][136], 17.4 KB

  const int m0 = blockIdx.x * 64;
  const int tid = threadIdx.x;
  const int lane = tid & 63;
  const int li = lane & 15, g = lane >> 4;
  const int wid = tid >> 6;
  const int wm = wid >> 2, wn = wid & 3;

  const int xr = tid >> 3;
  const int xc32 = (tid & 7) >> 1;
  const int xhf = tid & 1;
  const int wr = tid >> 2;
  const int wc = tid & 3;

  f32x4 acc[3][2][2] = {};

  // prologue: stage tile 0 -> buf 0 (4 loads/thread)
  {
    gl_lds16(X + (size_t)(m0 + xr) * 1024 + (xc32 ^ (xr & 3)) * 8 + xhf * 4,
             Xs + tid * 4);
#pragma unroll
    for (int z = 0; z < 3; ++z)
      gl_lds16(Wt + (size_t)z * 131072 + (size_t)wr * 1024 + (wc ^ (wr & 3)) * 8,
               Ws + z * 4096 + tid * 8);
  }
  int cur = 0, nxt = 1;
  for (int kt = 0; kt < 32; ++kt) {
    if (kt < 31) {  // issue stage(t+1) -> buf[nxt]; counted wait for tile t
      const int k0 = (kt + 1) * 32;
      gl_lds16(X + (size_t)(m0 + xr) * 1024 + k0 + (xc32 ^ (xr & 3)) * 8 + xhf * 4,
               Xs + nxt * 2048 + tid * 4);
#pragma unroll
      for (int z = 0; z < 3; ++z)
        gl_lds16(Wt + (size_t)z * 131072 + (size_t)wr * 1024 + k0 + (wc ^ (wr & 3)) * 8,
                 Ws + nxt * 12288 + z * 4096 + tid * 8);
      wait_vm4();
    } else {
      wait_vm0();
    }
    __builtin_amdgcn_s_barrier();  // tile kt ready; buf[nxt] safe (read@t-2)

    bf16x8 af[2];
#pragma unroll
    for (int mf = 0; mf < 2; ++mf) {
      int r = wm * 32 + mf * 16 + li;
      const float* xp = Xs + cur * 2048 + r * 32 + ((g ^ (r & 3)) * 8);
      f32x4 x0 = *(const f32x4*)xp;
      f32x4 x1 = *(const f32x4*)(xp + 4);
      union { bf16 h[8]; bf16x8 v; } u;
      u.h[0] = __float2bfloat16(x0[0]); u.h[1] = __float2bfloat16(x0[1]);
      u.h[2] = __float2bfloat16(x0[2]); u.h[3] = __float2bfloat16(x0[3]);
      u.h[4] = __float2bfloat16(x1[0]); u.h[5] = __float2bfloat16(x1[1]);
      u.h[6] = __float2bfloat16(x1[2]); u.h[7] = __float2bfloat16(x1[3]);
      af[mf] = u.v;
    }
#pragma unroll
    for (int z = 0; z < 3; ++z) {
#pragma unroll
      for (int nf = 0; nf < 2; ++nf) {
        int r = wn * 32 + nf * 16 + li;
        bf16x8 bfrag =
            *(const bf16x8*)(Ws + cur * 12288 + z * 4096 + r * 32 + ((g ^ (r & 3)) * 8));
#pragma unroll
        for (int mf = 0; mf < 2; ++mf)
          acc[z][mf][nf] = __builtin_amdgcn_mfma_f32_16x16x32_bf16(
              af[mf], bfrag, acc[z][mf][nf], 0, 0, 0);
      }
    }
    cur = nxt;
    nxt = nxt == 2 ? 0 : nxt + 1;
  }

  // Q, K epilogue (row-major). Q scale = log2(e)/sqrt(128).
#pragma unroll
  for (int z = 0; z < 2; ++z) {
    const float* bias = z == 0 ? bq : bk;
    bf16* Out = z == 0 ? Qo : Ko;
    const float scale = z == 0 ? 0.12752404368678202f : 1.0f;
#pragma unroll
    for (int nf = 0; nf < 2; ++nf) {
      int col = wn * 32 + nf * 16 + li;
      float bb = bias[col];
#pragma unroll
      for (int mf = 0; mf < 2; ++mf)
#pragma unroll
        for (int j = 0; j < 4; ++j) {
          int row = m0 + wm * 32 + mf * 16 + g * 4 + j;
          Out[(size_t)row * 128 + col] =
              __float2bfloat16((acc[z][mf][nf][j] + bb) * scale);
        }
    }
  }

  // V epilogue: bounce through LDS, write transposed Vt [B][128][S].
  __syncthreads();
#pragma unroll
  for (int nf = 0; nf < 2; ++nf) {
    int col = wn * 32 + nf * 16 + li;
    float bb = bv[col];
#pragma unroll
    for (int mf = 0; mf < 2; ++mf)
#pragma unroll
      for (int j = 0; j < 4; ++j) {
        int row = wm * 32 + mf * 16 + g * 4 + j;
        Vs[row * 136 + col] = __float2bfloat16(acc[2][mf][nf][j] + bb);
      }
  }
  __syncthreads();
  const int b = m0 >> 12;
  const int s_off = m0 & 4095;
#pragma unroll
  for (int t2 = 0; t2 < 2; ++t2) {
    int idx = tid + 512 * t2;
    int dv = idx & 127;
    int sg = idx >> 7;
    union { bf16 h[8]; u32x4 v; } u;
#pragma unroll
    for (int si = 0; si < 8; ++si) u.h[si] = Vs[(sg * 8 + si) * 136 + dv];
    *(u32x4*)(Vt + (size_t)(b * 128 + dv) * 4096 + s_off + sg * 8) = u.v;
  }
}

// ---------------------------------------------------------------------------
// 3) causal flash attention: 32x32x16 MFMA, in-register P.
//    256 thr = 4 waves x 32 q-rows (q-tile 128). dbuf K+V, counted vmcnt(8).
// ---------------------------------------------------------------------------
__global__ __launch_bounds__(256, 2) void k_attn(const bf16* __restrict__ Qb,
                                                 const bf16* __restrict__ Kb,
                                                 const bf16* __restrict__ Vt,
                                                 bf16* __restrict__ o_part,
                                                 float* __restrict__ l_part) {
  __shared__ __align__(16) bf16 Kls[2][64 * 128];  // 32 KB [kv][d] swizzled
  __shared__ __align__(16) bf16 Vls[2][128 * 64];  // 32 KB [dv][kv] swizzled

  const int bid = blockIdx.x;
  const int xcd = bid & 7;
  const int slot = xcd * 72 + (bid >> 3);     // bijective (576 = 8*72)
  const int b = slot / 144;
  const int s = 143 - (slot - b * 144);       // heavy-first work index
  const int widx = b * 144 + s;               // partial index (k_comb's)
  int qt = 0;
#pragma unroll
  for (int q2 = 1; q2 < 32; ++q2) {
    int M = q2 >> 2;
    if ((M + 1) * (2 * M + (q2 & 3)) <= s) qt = q2;
  }
  const int Mq = qt >> 2;
  const int chunk = s - (Mq + 1) * (2 * Mq + (qt & 3));
  const int ntiles = 2 * qt + 2;
  const int nch = (qt + 4) >> 2;
  const int clen = ntiles / nch;
  const int crem = ntiles - clen * nch;
  const int kt0 = chunk * clen + min(chunk, crem);
  const int kt1 = kt0 + clen + (chunk < crem ? 1 : 0) - 1;

  const int tid = threadIdx.x;
  const int lane = tid & 63;
  const int l31 = lane & 31;                  // q (and kv/dv row) index
  const int hl = lane >> 5;                   // lane half (k-dim half)
  const int w = tid >> 6;                     // wave 0..3, owns 32 q-rows

  const int qrow = b * 4096 + qt * 128 + w * 32 + l31;
  bf16x8 qf[8];
#pragma unroll
  for (int ks = 0; ks < 8; ++ks)
    qf[ks] = *(const bf16x8*)(Qb + (size_t)qrow * 128 + ks * 16 + hl * 8);

  f32x16 o[4] = {};
  f32x16 lacc = {};
  bf16x8 ones;
#pragma unroll
  for (int e = 0; e < 8; ++e) ones[e] = (__bf16)1.0f;

  const bf16* Vtb = Vt + (size_t)b * 128 * 4096;
  const int xaddr = (lane ^ 32) << 2;         // ds_bpermute byte addr

  {
    const int kv0 = kt0 * 64;
#pragma unroll
    for (int ii = 0; ii < 4; ++ii) {
      int c = tid + 256 * ii;
      int r = c >> 4, cc = c & 15;
      gl_lds16(Kb + (size_t)(b * 4096 + kv0 + r) * 128 + (cc ^ (r & 7)) * 8,
               &Kls[0][c * 8]);
      int r2 = c >> 3, cc2 = c & 7;
      gl_lds16(Vtb + (size_t)r2 * 4096 + kv0 + (cc2 ^ (r2 & 7)) * 8,
               &Vls[0][c * 8]);
    }
  }
  int cur = 0;
  for (int kt = kt0; kt <= kt1; ++kt) {
    if (kt < kt1) {
      const int kv0n = (kt + 1) * 64;
#pragma unroll
      for (int ii = 0; ii < 4; ++ii) {
        int c = tid + 256 * ii;
        int r = c >> 4, cc = c & 15;
        gl_lds16(Kb + (size_t)(b * 4096 + kv0n + r) * 128 + (cc ^ (r & 7)) * 8,
                 &Kls[cur ^ 1][c * 8]);
        int r2 = c >> 3, cc2 = c & 7;
        gl_lds16(Vtb + (size_t)r2 * 4096 + kv0n + (cc2 ^ (r2 & 7)) * 8,
                 &Vls[cur ^ 1][c * 8]);
      }
      wait_vm8();
    } else {
      wait_vm0();
    }
    __builtin_amdgcn_s_barrier();  // tile kt ready in buf[cur]

    const bf16* Kl = &Kls[cur][0];
    const bf16* Vl = &Vls[cur][0];
    const int kv0 = kt * 64;

    // S^T = K Q^T : st[t] = C[kv=32t.., q], A=K rows, B=Q^T
    f32x16 st[2] = {};
#pragma unroll
    for (int ks = 0; ks < 8; ++ks) {
#pragma unroll
      for (int t = 0; t < 2; ++t) {
        int r = t * 32 + l31;
        int ch = (2 * ks + hl) ^ (r & 7);
        bf16x8 kf = *(const bf16x8*)(Kl + r * 128 + ch * 8);
        st[t] = __builtin_amdgcn_mfma_f32_32x32x16_bf16(
            kf, qf[ks], st[t], 0, 0, 0);
      }
    }

    if (kt >= 2 * qt) {  // diagonal tiles: causal mask (kv > q)
      const int dk = kv0 - qt * 128;
      const int qloc = w * 32 + l31;
#pragma unroll
      for (int t = 0; t < 2; ++t)
#pragma unroll
        for (int reg = 0; reg < 16; ++reg) {
          int kvl = dk + t * 32 + (reg & 3) + 8 * (reg >> 2) + 4 * hl;
          if (kvl > qloc) st[t][reg] = -1e30f;
        }
    }

    // P = exp2(S) in-register; pack to bf16 dwords
    uint32_t D[2][8];
#pragma unroll
    for (int t = 0; t < 2; ++t)
#pragma unroll
      for (int i = 0; i < 8; ++i) {
        union { bf16 h2[2]; uint32_t u; } pu;
        pu.h2[0] = __float2bfloat16(exp2f(st[t][2 * i]));
        pu.h2[1] = __float2bfloat16(exp2f(st[t][2 * i + 1]));
        D[t][i] = pu.u;
      }

    // lane^32 exchange
    uint32_t Z[2][2][2];
#pragma unroll
    for (int t = 0; t < 2; ++t)
#pragma unroll
      for (int s2 = 0; s2 < 2; ++s2)
#pragma unroll
        for (int j = 0; j < 2; ++j) {
          uint32_t Y = hl ? D[t][4 * s2 + j] : D[t][4 * s2 + 2 + j];
          Z[t][s2][j] = (uint32_t)__builtin_amdgcn_ds_bpermute(xaddr, (int)Y);
        }

    // PV: O^T[dv][q] += V^T P^T per kv 16-slice; l via ones-MFMA
#pragma unroll
    for (int t = 0; t < 2; ++t) {
#pragma unroll
      for (int s2 = 0; s2 < 2; ++s2) {
        union { uint32_t u[4]; bf16x8 v; } pb;
        pb.u[0] = hl ? Z[t][s2][0] : D[t][4 * s2];
        pb.u[1] = hl ? Z[t][s2][1] : D[t][4 * s2 + 1];
        pb.u[2] = hl ? D[t][4 * s2 + 2] : Z[t][s2][0];
        pb.u[3] = hl ? D[t][4 * s2 + 3] : Z[t][s2][1];
#pragma unroll
        for (int ds = 0; ds < 4; ++ds) {
          int r = ds * 32 + l31;
          int ch = (4 * t + 2 * s2 + hl) ^ (r & 7);
          bf16x8 vf = *(const bf16x8*)(Vl + r * 64 + ch * 8);
          o[ds] = __builtin_amdgcn_mfma_f32_32x32x16_bf16(
              vf, pb.v, o[ds], 0, 0, 0);
        }
        lacc = __builtin_amdgcn_mfma_f32_32x32x16_bf16(
            ones, pb.v, lacc, 0, 0, 0);
      }
    }
    __builtin_amdgcn_s_barrier();  // readers done before buf[cur] overwrite
    cur ^= 1;
  }

  // partials at WORK index widx
  bf16* op = o_part + (size_t)widx * (128 * 128);
  float* lp = l_part + widx * 128;
  const int qloc = w * 32 + l31;
  if (hl == 0) lp[qloc] = lacc[0];
#pragma unroll
  for (int ds = 0; ds < 4; ++ds)
#pragma unroll
    for (int a = 0; a < 4; ++a) {
      union { bf16 h4[4]; u32x2 v; } u;
#pragma unroll
      for (int j = 0; j < 4; ++j)
        u.h4[j] = __float2bfloat16(o[ds][4 * a + j]);
      *(u32x2*)(op + (size_t)qloc * 128 + ds * 32 + 8 * a + 4 * hl) = u.v;
    }
}

// ---------------------------------------------------------------------------
// 4) combine chunk partials: 8 cols/thread (u32x4 loads).
// ---------------------------------------------------------------------------
__global__ __launch_bounds__(256) void k_comb(const bf16* __restrict__ op,
                                              const float* __restrict__ lp,
                                              float* __restrict__ out) {
  int i = blockIdx.x * 256 + threadIdx.x;  // 8-col group index, < 262144
  int row = i >> 4;
  int col8 = (i & 15) * 8;
  int b = row >> 12;
  int rb = row & 4095;
  int qt = rb >> 7;
  int lr = rb & 127;
  int M = qt >> 2;
  int base = b * 144 + (M + 1) * (2 * M + (qt & 3));
  int n = (qt + 4) >> 2;
  float l = 0.0f;
  float acc[8] = {};
  for (int c = 0; c < n; ++c) {
    l += lp[(base + c) * 128 + lr];
    union { bf16 h[8]; u32x4 v; } u;
    u.v = *(const u32x4*)(op + (size_t)(base + c) * 16384 + lr * 128 + col8);
#pragma unroll
    for (int j = 0; j < 8; ++j) acc[j] += __bfloat162float(u.h[j]);
  }
  float linv = 1.0f / l;
  float4 r0, r1;
  r0.x = acc[0] * linv; r0.y = acc[1] * linv;
  r0.z = acc[2] * linv; r0.w = acc[3] * linv;
  r1.x = acc[4] * linv; r1.y = acc[5] * linv;
  r1.z = acc[6] * linv; r1.w = acc[7] * linv;
  ((float4*)out)[i * 2] = r0;
  ((float4*)out)[i * 2 + 1] = r1;
}

// ---------------------------------------------------------------------------
extern "C" void kernel_launch(void* const* d_in, const int* in_sizes, int n_in,
                              void* d_out, int out_size, void* d_ws, size_t ws_size,
                              hipStream_t stream) {
  const float* X  = (const float*)d_in[0];
  const float* Wq = (const float*)d_in[1];
  const float* bq = (const float*)d_in[2];
  const float* Wk = (const float*)d_in[3];
  const float* bk = (const float*)d_in[4];
  const float* Wv = (const float*)d_in[5];
  const float* bv = (const float*)d_in[6];
  float* out = (float*)d_out;

  char* ws = (char*)d_ws;
  // layout (bytes) — fully disjoint, extent 32,538,624 (proven size)
  bf16* Wt  = (bf16*)(ws + 0);              //    786,432
  bf16* Qb  = (bf16*)(ws + 786432);         //  4,194,304
  bf16* Kb  = (bf16*)(ws + 4980736);        //  4,194,304
  bf16* Vt  = (bf16*)(ws + 9175040);        //  4,194,304
  bf16* o_part = (bf16*)(ws + 13369344);    // 18,874,368 (576*128*128*2)
  float* l_part = (float*)(ws + 32243712);  //    294,912

  k_wt<<<dim3(16, 2, 3), dim3(256), 0, stream>>>(Wq, Wk, Wv, Wt);
  k_qkv<<<dim3(256), dim3(512), 0, stream>>>(X, Wt, bq, bk, bv, Qb, Kb, Vt);
  k_attn<<<dim3(576), dim3(256), 0, stream>>>(Qb, Kb, Vt, o_part, l_part);
  k_comb<<<dim3(1024), dim3(256), 0, stream>>>(o_part, l_part, out);
}